// Round 1
// 470.456 us; speedup vs baseline: 1.0057x; 1.0057x over previous
//
#include <hip/hip_runtime.h>
#include <math.h>

// attention_block: B=8, C_IN=4, C_OUT=64, H=8, W=2048, d=C_OUT*H=512
// out = [x_out (8*512*2048) fp32] ++ [masked pre-softmax scores (8*2048*2048) fp32]
//
// R6 (polish of R5, numerics bit-identical):
//  - scores_mfma: staging via __builtin_amdgcn_global_load_lds width=16 (no VGPR
//    roundtrip), global-source chunk permutation chunk^=(row>>1)&3 with matching
//    swizzled ds_read_b128 -> 2-way banks max (free). Same 2-barrier m97 shape.
//  - out_mfma: 2-deep pipeline (T14 async-split): issue next chunk's V
//    global_load_lds + S register loads BEFORE current MFMAs, exp/split+ds_write P
//    AFTER them; ONE barrier per chunk. Double-buffered 64 KB LDS (grid caps at
//    2 blocks/CU anyway). Same chunk swizzle kills the 8-way read conflicts.
//
// ws layout unchanged from R5 (~100.8 MB):
//   Qhi,Qlo,Khi,Klo: [b][w][d] bf16; Vhi,Vlo: [b][d][w] bf16; mrow,invrow: [b*W] f32
//
// Ref scores contain -inf; we write finite NEG_BIG (-3e38) instead.

#define B_ 8
#define W_ 2048
#define D_ 512
#define SCALE_ 0.04419417382415922f  // 1/sqrt(512)
#define NEG_BIG_ (-3.0e38f)

typedef __attribute__((ext_vector_type(8))) short bf16x8;
typedef __attribute__((ext_vector_type(4))) float f32x4;

__device__ __forceinline__ unsigned short f2bf(float x) {  // RNE truncate f32->bf16
  unsigned int u = __float_as_uint(x);
  u += 0x7fffu + ((u >> 16) & 1u);
  return (unsigned short)(u >> 16);
}
__device__ __forceinline__ float bf2f(unsigned short h) {
  return __uint_as_float(((unsigned int)h) << 16);
}
__device__ __forceinline__ void split2(float x, unsigned short& hi, unsigned short& lo) {
  hi = f2bf(x);
  lo = f2bf(x - bf2f(hi));
}

// async global->LDS, 16B per lane. LDS dest must be wave-uniform base + lane*16
// (we always pass base + t*16 so the per-lane ptr matches HW behavior).
__device__ __forceinline__ void gl16(const unsigned short* g, unsigned short* l) {
  __builtin_amdgcn_global_load_lds(
      (__attribute__((address_space(1))) void*)const_cast<unsigned short*>(g),
      (__attribute__((address_space(3))) void*)l, 16, 0, 0);
}

// swizzled fragment address in a [128][32]-short tile: row*64B + (lq^f(row))*16B.
// f(row)=(row>>1)&3 spreads 16-row b128 column reads over 8 bank-quads (2-way=free).
__device__ __forceinline__ int swz(int row, int lq) {
  return row * 32 + ((lq ^ ((row >> 1) & 3)) << 3);
}

// ---- projection: q,k with d-fastest indexing -> Q~,K~ [b][w][d] coalesced ----
__global__ __launch_bounds__(256) void proj_qk(
    const float* __restrict__ x,
    const float* __restrict__ Wq, const float* __restrict__ bq,
    const float* __restrict__ Wk, const float* __restrict__ bk,
    unsigned short* __restrict__ Qhi, unsigned short* __restrict__ Qlo,
    unsigned short* __restrict__ Khi, unsigned short* __restrict__ Klo) {
  int idx = blockIdx.x * 256 + threadIdx.x;   // (b, w, d) d-fastest
  int d = idx & (D_ - 1);
  int w = (idx >> 9) & (W_ - 1);
  int b = idx >> 20;
  int o = d >> 3, h = d & 7;
  const float* xp = x + (((size_t)b * 4) * 8 + h) * W_ + w;   // c-stride 8*W_
  float x0 = xp[0], x1 = xp[8 * W_], x2 = xp[16 * W_], x3 = xp[24 * W_];
  const float* wq = Wq + o * 4;
  const float* wk = Wk + o * 4;
  float q = bq[o] + wq[0] * x0 + wq[1] * x1 + wq[2] * x2 + wq[3] * x3;
  float k = bk[o] + wk[0] * x0 + wk[1] * x1 + wk[2] * x2 + wk[3] * x3;
  unsigned short h16, l16;
  split2(q, h16, l16); Qhi[idx] = h16; Qlo[idx] = l16;
  split2(k, h16, l16); Khi[idx] = h16; Klo[idx] = l16;
}

// ---- projection: v with w-fastest indexing -> V [b][d][w] coalesced ----
__global__ __launch_bounds__(256) void proj_v(
    const float* __restrict__ x,
    const float* __restrict__ Wv, const float* __restrict__ bv,
    unsigned short* __restrict__ Vhi, unsigned short* __restrict__ Vlo) {
  int idx = blockIdx.x * 256 + threadIdx.x;   // (b, d, w) w-fastest
  int w = idx & (W_ - 1);
  int rest = idx >> 11;
  int d = rest & (D_ - 1);
  int b = rest >> 9;
  int o = d >> 3, h = d & 7;
  const float* xp = x + (((size_t)b * 4) * 8 + h) * W_ + w;
  float x0 = xp[0], x1 = xp[8 * W_], x2 = xp[16 * W_], x3 = xp[24 * W_];
  const float* wv = Wv + o * 4;
  float v = bv[o] + wv[0] * x0 + wv[1] * x1 + wv[2] * x2 + wv[3] * x3;
  unsigned short h16, l16;
  split2(v, h16, l16); Vhi[idx] = h16; Vlo[idx] = l16;
}

// ---- scores: S[k][l] = sum_d Q~[k][d]*K~[l][d] * SCALE, causal mask ----
// 128x128 block tile, 4 waves of 64x64, 16x16x32 bf16 MFMA, split-precision.
__global__ __launch_bounds__(256) void scores_mfma(
    const unsigned short* __restrict__ Qhi, const unsigned short* __restrict__ Qlo,
    const unsigned short* __restrict__ Khi, const unsigned short* __restrict__ Klo,
    float* __restrict__ S, const int* __restrict__ causal_p) {
  int b = blockIdx.z;
  int k0 = blockIdx.y * 128;
  int l0 = blockIdx.x * 128;
  int causal = *causal_p;
  int t = threadIdx.x;
  float* Sb = S + (size_t)b * W_ * W_;

  if (causal && (l0 + 127 < k0)) {   // tile fully below diagonal
    float4 nb = make_float4(NEG_BIG_, NEG_BIG_, NEG_BIG_, NEG_BIG_);
    int row = t >> 1, c0 = (t & 1) * 64;
#pragma unroll
    for (int j = 0; j < 16; j++)
      *(float4*)&Sb[(size_t)(k0 + row) * W_ + l0 + c0 + j * 4] = nb;
    return;
  }

  __shared__ __align__(16) unsigned short qh_s[128 * 32], ql_s[128 * 32];
  __shared__ __align__(16) unsigned short kh_s[128 * 32], kl_s[128 * 32];

  int wave = t >> 6, lane = t & 63;
  int wk0 = (wave >> 1) * 64, wl0 = (wave & 1) * 64;
  int lr = lane & 15, lq = lane >> 4;

  const unsigned short* Qhb = Qhi + ((size_t)b * W_ + k0) * D_;
  const unsigned short* Qlb = Qlo + ((size_t)b * W_ + k0) * D_;
  const unsigned short* Khb = Khi + ((size_t)b * W_ + l0) * D_;
  const unsigned short* Klb = Klo + ((size_t)b * W_ + l0) * D_;

  // staging geometry: 512 slots = 128 rows x 4 chunks; thread owns slots t, t+256.
  // Global source permuted (chunk c = qs ^ f(row)); LDS dest linear (slot*16B).
  int srow0 = t >> 2, sq = t & 3;
  int srow1 = srow0 + 64;
  size_t g0 = (size_t)srow0 * D_ + ((sq ^ ((srow0 >> 1) & 3)) << 3);
  size_t g1 = (size_t)srow1 * D_ + ((sq ^ ((srow1 >> 1) & 3)) << 3);
  int a0 = t * 8, a1 = t * 8 + 2048;   // shorts

  f32x4 acc[4][4];
#pragma unroll
  for (int i = 0; i < 4; i++)
#pragma unroll
    for (int j = 0; j < 4; j++) acc[i][j] = (f32x4){0.f, 0.f, 0.f, 0.f};

  for (int d0 = 0; d0 < D_; d0 += 32) {
    gl16(Qhb + g0 + d0, &qh_s[a0]);
    gl16(Qhb + g1 + d0, &qh_s[a1]);
    gl16(Qlb + g0 + d0, &ql_s[a0]);
    gl16(Qlb + g1 + d0, &ql_s[a1]);
    gl16(Khb + g0 + d0, &kh_s[a0]);
    gl16(Khb + g1 + d0, &kh_s[a1]);
    gl16(Klb + g0 + d0, &kl_s[a0]);
    gl16(Klb + g1 + d0, &kl_s[a1]);
    __syncthreads();   // drains vmcnt for global_load_lds

    bf16x8 ah[4], al[4], bh[4], bl[4];
#pragma unroll
    for (int mt = 0; mt < 4; mt++) {
      int a = swz(wk0 + mt * 16 + lr, lq);
      ah[mt] = *(const bf16x8*)&qh_s[a];
      al[mt] = *(const bf16x8*)&ql_s[a];
    }
#pragma unroll
    for (int nt = 0; nt < 4; nt++) {
      int a = swz(wl0 + nt * 16 + lr, lq);
      bh[nt] = *(const bf16x8*)&kh_s[a];
      bl[nt] = *(const bf16x8*)&kl_s[a];
    }
#pragma unroll
    for (int mt = 0; mt < 4; mt++)
#pragma unroll
      for (int nt = 0; nt < 4; nt++) {
        acc[mt][nt] = __builtin_amdgcn_mfma_f32_16x16x32_bf16(ah[mt], bh[nt], acc[mt][nt], 0, 0, 0);
        acc[mt][nt] = __builtin_amdgcn_mfma_f32_16x16x32_bf16(ah[mt], bl[nt], acc[mt][nt], 0, 0, 0);
        acc[mt][nt] = __builtin_amdgcn_mfma_f32_16x16x32_bf16(al[mt], bh[nt], acc[mt][nt], 0, 0, 0);
      }
    __syncthreads();
  }

#pragma unroll
  for (int mt = 0; mt < 4; mt++)
#pragma unroll
    for (int nt = 0; nt < 4; nt++)
#pragma unroll
      for (int r = 0; r < 4; r++) {
        int k = k0 + wk0 + mt * 16 + lq * 4 + r;
        int l = l0 + wl0 + nt * 16 + lr;
        float s = acc[mt][nt][r] * SCALE_;
        if (causal && (l < k || s == 0.0f)) s = NEG_BIG_;  // faithful triu + zero->mask
        Sb[(size_t)k * W_ + l] = s;
      }
}

// ---- per-row softmax stats: m = max, inv = 1/sum(exp(s-m)) ----
__global__ __launch_bounds__(256) void softmax_stats_kernel(
    const float* __restrict__ S, float* __restrict__ mrow, float* __restrict__ invrow) {
  int row = blockIdx.x;  // 0 .. B_*W_-1
  const float* Sr = S + (size_t)row * W_;
  int t = threadIdx.x;
  float v[8];
  *(float4*)&v[0] = *(const float4*)&Sr[t * 8];
  *(float4*)&v[4] = *(const float4*)&Sr[t * 8 + 4];
  float mx = -INFINITY;
#pragma unroll
  for (int r = 0; r < 8; r++) mx = fmaxf(mx, v[r]);
#pragma unroll
  for (int off = 1; off < 64; off <<= 1) mx = fmaxf(mx, __shfl_xor(mx, off, 64));
  __shared__ float redm[4];
  __shared__ float reds[4];
  int wid = t >> 6, lane = t & 63;
  if (lane == 0) redm[wid] = mx;
  __syncthreads();
  mx = fmaxf(fmaxf(redm[0], redm[1]), fmaxf(redm[2], redm[3]));
  float sum = 0.f;
#pragma unroll
  for (int r = 0; r < 8; r++) sum += __expf(v[r] - mx);
#pragma unroll
  for (int off = 1; off < 64; off <<= 1) sum += __shfl_xor(sum, off, 64);
  if (lane == 0) reds[wid] = sum;
  __syncthreads();
  if (t == 0) {
    float s = reds[0] + reds[1] + reds[2] + reds[3];
    mrow[row] = mx;
    invrow[row] = 1.0f / s;
  }
}

// ---- out: O[d][k] = sum_l V[d][l] * P[k][l], P = exp(S-m)*inv (split bf16) ----
// 128(d) x 128(k) block tile, 4 waves of 64x64, l-chunks of 32 from k0.
// 2-deep pipeline: stage chunk i+1 (V via global_load_lds, S into regs) before
// chunk i's MFMAs; exp/split + P ds_write after them; ONE barrier per chunk.
__global__ __launch_bounds__(256) void out_mfma(
    const unsigned short* __restrict__ Vhi, const unsigned short* __restrict__ Vlo,
    const float* __restrict__ S,
    const float* __restrict__ mrow, const float* __restrict__ invrow,
    float* __restrict__ O, const int* __restrict__ causal_p) {
  int b = blockIdx.z;
  int d0 = blockIdx.y * 128;
  int k0 = blockIdx.x * 128;
  int causal = *causal_p;
  int t = threadIdx.x;
  int wave = t >> 6, lane = t & 63;
  int wd0 = (wave >> 1) * 64, wk0 = (wave & 1) * 64;
  int lr = lane & 15, lq = lane >> 4;

  __shared__ __align__(16) unsigned short vh_s[2][128 * 32], vl_s[2][128 * 32];
  __shared__ __align__(16) unsigned short ph_s[2][128 * 32], pl_s[2][128 * 32];

  const unsigned short* Vhb = Vhi + ((size_t)b * D_ + d0) * W_;
  const unsigned short* Vlb = Vlo + ((size_t)b * D_ + d0) * W_;
  const float* Sb = S + (size_t)b * W_ * W_ + (size_t)k0 * W_;

  // staging geometry: 512 slots = 128 rows x 4 chunks; thread owns slots t, t+256.
  int rowA = t >> 2, qs = t & 3;
  int rowB = rowA + 64;
  int cA = qs ^ ((rowA >> 1) & 3);          // swizzled chunk this thread fetches/writes
  int cB = qs ^ ((rowB >> 1) & 3);
  int ldsA = t * 8, ldsB = t * 8 + 2048;    // linear LDS dest (shorts)
  int pA = rowA * 32 + cA * 8;              // swizzled ds_write addr for P
  int pB = rowB * 32 + cB * 8;

  const unsigned short* VhA = Vhb + (size_t)rowA * W_ + cA * 8;
  const unsigned short* VhB = Vhb + (size_t)rowB * W_ + cB * 8;
  const unsigned short* VlA = Vlb + (size_t)rowA * W_ + cA * 8;
  const unsigned short* VlB = Vlb + (size_t)rowB * W_ + cB * 8;
  const float* SA = Sb + (size_t)rowA * W_ + qs * 8;   // natural chunk for S reads
  const float* SB = Sb + (size_t)rowB * W_ + qs * 8;
  float mA = mrow[(size_t)b * W_ + k0 + rowA], iA = invrow[(size_t)b * W_ + k0 + rowA];
  float mB = mrow[(size_t)b * W_ + k0 + rowB], iB = invrow[(size_t)b * W_ + k0 + rowB];

  f32x4 acc[4][4];
#pragma unroll
  for (int i = 0; i < 4; i++)
#pragma unroll
    for (int j = 0; j < 4; j++) acc[i][j] = (f32x4){0.f, 0.f, 0.f, 0.f};

  int lstart = causal ? k0 : 0;   // P[k][l]=0 for l<k
  int nch = (W_ - lstart) >> 5;

  float4 sa0, sa1, sb0, sb1;
  auto stageV = [&](int buf, int l) {
    gl16(VhA + l, &vh_s[buf][ldsA]);
    gl16(VhB + l, &vh_s[buf][ldsB]);
    gl16(VlA + l, &vl_s[buf][ldsA]);
    gl16(VlB + l, &vl_s[buf][ldsB]);
  };
  auto loadS = [&](int l) {
    sa0 = *(const float4*)&SA[l]; sa1 = *(const float4*)&SA[l + 4];
    sb0 = *(const float4*)&SB[l]; sb1 = *(const float4*)&SB[l + 4];
  };
  auto writeP = [&](int buf) {
    float p[8];
    unsigned short hi8[8] __attribute__((aligned(16)));
    unsigned short lo8[8] __attribute__((aligned(16)));
    p[0] = __expf(sa0.x - mA) * iA; p[1] = __expf(sa0.y - mA) * iA;
    p[2] = __expf(sa0.z - mA) * iA; p[3] = __expf(sa0.w - mA) * iA;
    p[4] = __expf(sa1.x - mA) * iA; p[5] = __expf(sa1.y - mA) * iA;
    p[6] = __expf(sa1.z - mA) * iA; p[7] = __expf(sa1.w - mA) * iA;
#pragma unroll
    for (int j = 0; j < 8; j++) split2(p[j], hi8[j], lo8[j]);
    *(uint4*)&ph_s[buf][pA] = *(uint4*)hi8;
    *(uint4*)&pl_s[buf][pA] = *(uint4*)lo8;
    p[0] = __expf(sb0.x - mB) * iB; p[1] = __expf(sb0.y - mB) * iB;
    p[2] = __expf(sb0.z - mB) * iB; p[3] = __expf(sb0.w - mB) * iB;
    p[4] = __expf(sb1.x - mB) * iB; p[5] = __expf(sb1.y - mB) * iB;
    p[6] = __expf(sb1.z - mB) * iB; p[7] = __expf(sb1.w - mB) * iB;
#pragma unroll
    for (int j = 0; j < 8; j++) split2(p[j], hi8[j], lo8[j]);
    *(uint4*)&ph_s[buf][pB] = *(uint4*)hi8;
    *(uint4*)&pl_s[buf][pB] = *(uint4*)lo8;
  };

  // prologue: chunk 0 into buf 0
  stageV(0, lstart);
  loadS(lstart);
  writeP(0);
  __syncthreads();

  for (int ci = 0; ci < nch; ci++) {
    int cur = ci & 1, nxt = cur ^ 1;
    bool pre = (ci + 1 < nch);
    int ln = lstart + (ci + 1) * 32;
    if (pre) {                 // issue next chunk's loads early (hide under MFMA)
      stageV(nxt, ln);
      loadS(ln);
    }

    bf16x8 ah[4], al[4], bh[4], bl[4];
#pragma unroll
    for (int mt = 0; mt < 4; mt++) {
      int a = swz(wd0 + mt * 16 + lr, lq);
      ah[mt] = *(const bf16x8*)&vh_s[cur][a];
      al[mt] = *(const bf16x8*)&vl_s[cur][a];
    }
#pragma unroll
    for (int nt = 0; nt < 4; nt++) {
      int a = swz(wk0 + nt * 16 + lr, lq);
      bh[nt] = *(const bf16x8*)&ph_s[cur][a];
      bl[nt] = *(const bf16x8*)&pl_s[cur][a];
    }
#pragma unroll
    for (int mt = 0; mt < 4; mt++)
#pragma unroll
      for (int nt = 0; nt < 4; nt++) {
        acc[mt][nt] = __builtin_amdgcn_mfma_f32_16x16x32_bf16(ah[mt], bh[nt], acc[mt][nt], 0, 0, 0);
        acc[mt][nt] = __builtin_amdgcn_mfma_f32_16x16x32_bf16(ah[mt], bl[nt], acc[mt][nt], 0, 0, 0);
        acc[mt][nt] = __builtin_amdgcn_mfma_f32_16x16x32_bf16(al[mt], bh[nt], acc[mt][nt], 0, 0, 0);
      }

    if (pre) writeP(nxt);      // exp/split + ds_write after MFMAs (loads landed)
    __syncthreads();           // one barrier per chunk: drains vmcnt + lgkm
  }

#pragma unroll
  for (int mt = 0; mt < 4; mt++)
#pragma unroll
    for (int nt = 0; nt < 4; nt++)
#pragma unroll
      for (int r = 0; r < 4; r++) {
        int d = d0 + wd0 + mt * 16 + lq * 4 + r;
        int k = k0 + wk0 + nt * 16 + lr;
        O[((size_t)b * D_ + d) * W_ + k] = acc[mt][nt][r];
      }
}

extern "C" void kernel_launch(void* const* d_in, const int* in_sizes, int n_in,
                              void* d_out, int out_size, void* d_ws, size_t ws_size,
                              hipStream_t stream) {
  const float* x  = (const float*)d_in[0];
  const float* Wq = (const float*)d_in[1];
  const float* bq = (const float*)d_in[2];
  const float* Wk = (const float*)d_in[3];
  const float* bk = (const float*)d_in[4];
  const float* Wv = (const float*)d_in[5];
  const float* bv = (const float*)d_in[6];
  const int* causal = (const int*)d_in[7];

  float* out = (float*)d_out;
  float* x_out = out;                                   // 8*512*2048
  float* S = out + (size_t)B_ * D_ * W_;                // 8*2048*2048

  const size_t NQ = (size_t)B_ * W_ * D_;               // 8,388,608
  unsigned short* wsu = (unsigned short*)d_ws;
  unsigned short* Qhi = wsu;
  unsigned short* Qlo = wsu + NQ;
  unsigned short* Khi = wsu + 2 * NQ;
  unsigned short* Klo = wsu + 3 * NQ;
  unsigned short* Vhi = wsu + 4 * NQ;
  unsigned short* Vlo = wsu + 5 * NQ;
  float* mrow   = (float*)(wsu + 6 * NQ);               // B_*W_ = 16384
  float* invrow = mrow + (size_t)B_ * W_;

  int nproj = (int)(NQ / 256);
  proj_qk<<<nproj, 256, 0, stream>>>(x, Wq, bq, Wk, bk, Qhi, Qlo, Khi, Klo);
  proj_v<<<nproj, 256, 0, stream>>>(x, Wv, bv, Vhi, Vlo);
  scores_mfma<<<dim3(W_ / 128, W_ / 128, B_), 256, 0, stream>>>(Qhi, Qlo, Khi, Klo, S, causal);
  softmax_stats_kernel<<<B_ * W_, 256, 0, stream>>>(S, mrow, invrow);
  out_mfma<<<dim3(W_ / 128, D_ / 128, B_), 256, 0, stream>>>(Vhi, Vlo, S, mrow, invrow,
                                                             x_out, causal);
}

// Round 2
// 434.128 us; speedup vs baseline: 1.0899x; 1.0837x over previous
//
#include <hip/hip_runtime.h>
#include <math.h>

// attention_block: B=8, C_IN=4, C_OUT=64, H=8, W=2048, d=C_OUT*H=512
// out = [x_out (8*512*2048) fp32] ++ [masked pre-softmax scores (8*2048*2048) fp32]
//
// R7: restructure out kernel. R6 post-mortem: bank conflicts were 0 yet time
// unchanged -> stall = S->exp->split->ds_write chain, repeated 4x redundantly
// (each 128d-tile recomputed P). New out_fused: block = (b, k0, d-half of 256),
// grid 256 blocks x 512 threads (8 waves of 64d x 64k). P computed ONCE per
// block (exp VALU /4 chip-wide, S fetch /2), 384 MFMAs per barrier (2x density).
// Bijective XCD-chunk swizzle puts the two d-halves (same S rows) on one XCD.
// scores_mfma: same XCD-chunk swizzle (per-XCD chunk = one b's full tile grid).
// Numerics bit-identical to R5/R6 (same exp/split path, same MFMA order).
//
// ws layout unchanged (~100.8 MB):
//   Qhi,Qlo,Khi,Klo: [b][w][d] bf16; Vhi,Vlo: [b][d][w] bf16; mrow,invrow: [b*W] f32

#define B_ 8
#define W_ 2048
#define D_ 512
#define SCALE_ 0.04419417382415922f  // 1/sqrt(512)
#define NEG_BIG_ (-3.0e38f)

typedef __attribute__((ext_vector_type(8))) short bf16x8;
typedef __attribute__((ext_vector_type(4))) float f32x4;

__device__ __forceinline__ unsigned short f2bf(float x) {  // RNE truncate f32->bf16
  unsigned int u = __float_as_uint(x);
  u += 0x7fffu + ((u >> 16) & 1u);
  return (unsigned short)(u >> 16);
}
__device__ __forceinline__ float bf2f(unsigned short h) {
  return __uint_as_float(((unsigned int)h) << 16);
}
__device__ __forceinline__ void split2(float x, unsigned short& hi, unsigned short& lo) {
  hi = f2bf(x);
  lo = f2bf(x - bf2f(hi));
}

// async global->LDS, 16B per lane (dest = wave-uniform base + lane*16 pattern).
__device__ __forceinline__ void gl16(const unsigned short* g, unsigned short* l) {
  __builtin_amdgcn_global_load_lds(
      (__attribute__((address_space(1))) void*)const_cast<unsigned short*>(g),
      (__attribute__((address_space(3))) void*)l, 16, 0, 0);
}

// swizzled fragment address in a [R][32]-short tile: row*64B + (lq^f(row))*16B.
// f(row)=(row>>1)&3: within a 16-lane b128 phase, lanes hit 8 distinct 16B slots
// 2-way each = conflict-free (verified R6: SQ_LDS_BANK_CONFLICT = 0).
__device__ __forceinline__ int swz(int row, int lq) {
  return row * 32 + ((lq ^ ((row >> 1) & 3)) << 3);
}

// ---- projection: q,k with d-fastest indexing -> Q~,K~ [b][w][d] coalesced ----
__global__ __launch_bounds__(256) void proj_qk(
    const float* __restrict__ x,
    const float* __restrict__ Wq, const float* __restrict__ bq,
    const float* __restrict__ Wk, const float* __restrict__ bk,
    unsigned short* __restrict__ Qhi, unsigned short* __restrict__ Qlo,
    unsigned short* __restrict__ Khi, unsigned short* __restrict__ Klo) {
  int idx = blockIdx.x * 256 + threadIdx.x;   // (b, w, d) d-fastest
  int d = idx & (D_ - 1);
  int w = (idx >> 9) & (W_ - 1);
  int b = idx >> 20;
  int o = d >> 3, h = d & 7;
  const float* xp = x + (((size_t)b * 4) * 8 + h) * W_ + w;   // c-stride 8*W_
  float x0 = xp[0], x1 = xp[8 * W_], x2 = xp[16 * W_], x3 = xp[24 * W_];
  const float* wq = Wq + o * 4;
  const float* wk = Wk + o * 4;
  float q = bq[o] + wq[0] * x0 + wq[1] * x1 + wq[2] * x2 + wq[3] * x3;
  float k = bk[o] + wk[0] * x0 + wk[1] * x1 + wk[2] * x2 + wk[3] * x3;
  unsigned short h16, l16;
  split2(q, h16, l16); Qhi[idx] = h16; Qlo[idx] = l16;
  split2(k, h16, l16); Khi[idx] = h16; Klo[idx] = l16;
}

// ---- projection: v with w-fastest indexing -> V [b][d][w] coalesced ----
__global__ __launch_bounds__(256) void proj_v(
    const float* __restrict__ x,
    const float* __restrict__ Wv, const float* __restrict__ bv,
    unsigned short* __restrict__ Vhi, unsigned short* __restrict__ Vlo) {
  int idx = blockIdx.x * 256 + threadIdx.x;   // (b, d, w) w-fastest
  int w = idx & (W_ - 1);
  int rest = idx >> 11;
  int d = rest & (D_ - 1);
  int b = rest >> 9;
  int o = d >> 3, h = d & 7;
  const float* xp = x + (((size_t)b * 4) * 8 + h) * W_ + w;
  float x0 = xp[0], x1 = xp[8 * W_], x2 = xp[16 * W_], x3 = xp[24 * W_];
  const float* wv = Wv + o * 4;
  float v = bv[o] + wv[0] * x0 + wv[1] * x1 + wv[2] * x2 + wv[3] * x3;
  unsigned short h16, l16;
  split2(v, h16, l16); Vhi[idx] = h16; Vlo[idx] = l16;
}

// ---- scores: S[k][l] = sum_d Q~[k][d]*K~[l][d] * SCALE, causal mask ----
// 128x128 block tile, 4 waves of 64x64, 16x16x32 bf16 MFMA, split-precision.
// XCD-chunk swizzle: per-XCD logical chunk of 256 blocks = one b's tile grid.
__global__ __launch_bounds__(256) void scores_mfma(
    const unsigned short* __restrict__ Qhi, const unsigned short* __restrict__ Qlo,
    const unsigned short* __restrict__ Khi, const unsigned short* __restrict__ Klo,
    float* __restrict__ S, const int* __restrict__ causal_p) {
  // flat dispatch id (x fastest); nwg = 2048, divisible by 8.
  int f = (blockIdx.z * 16 + blockIdx.y) * 16 + blockIdx.x;
  int lf = (f & 7) * 256 + (f >> 3);   // XCD j owns logical [j*256,(j+1)*256)
  int b = lf >> 8;
  int k0 = ((lf >> 4) & 15) * 128;
  int l0 = (lf & 15) * 128;
  int causal = *causal_p;
  int t = threadIdx.x;
  float* Sb = S + (size_t)b * W_ * W_;

  if (causal && (l0 + 127 < k0)) {   // tile fully below diagonal
    float4 nb = make_float4(NEG_BIG_, NEG_BIG_, NEG_BIG_, NEG_BIG_);
    int row = t >> 1, c0 = (t & 1) * 64;
#pragma unroll
    for (int j = 0; j < 16; j++)
      *(float4*)&Sb[(size_t)(k0 + row) * W_ + l0 + c0 + j * 4] = nb;
    return;
  }

  __shared__ __align__(16) unsigned short qh_s[128 * 32], ql_s[128 * 32];
  __shared__ __align__(16) unsigned short kh_s[128 * 32], kl_s[128 * 32];

  int wave = t >> 6, lane = t & 63;
  int wk0 = (wave >> 1) * 64, wl0 = (wave & 1) * 64;
  int lr = lane & 15, lq = lane >> 4;

  const unsigned short* Qhb = Qhi + ((size_t)b * W_ + k0) * D_;
  const unsigned short* Qlb = Qlo + ((size_t)b * W_ + k0) * D_;
  const unsigned short* Khb = Khi + ((size_t)b * W_ + l0) * D_;
  const unsigned short* Klb = Klo + ((size_t)b * W_ + l0) * D_;

  // staging: 512 slots = 128 rows x 4 chunks; thread owns slots t, t+256.
  // Global source chunk-permuted; LDS dest linear.
  int srow0 = t >> 2, sq = t & 3;
  int srow1 = srow0 + 64;
  size_t g0 = (size_t)srow0 * D_ + ((sq ^ ((srow0 >> 1) & 3)) << 3);
  size_t g1 = (size_t)srow1 * D_ + ((sq ^ ((srow1 >> 1) & 3)) << 3);
  int a0 = t * 8, a1 = t * 8 + 2048;   // shorts

  f32x4 acc[4][4];
#pragma unroll
  for (int i = 0; i < 4; i++)
#pragma unroll
    for (int j = 0; j < 4; j++) acc[i][j] = (f32x4){0.f, 0.f, 0.f, 0.f};

  for (int d0 = 0; d0 < D_; d0 += 32) {
    gl16(Qhb + g0 + d0, &qh_s[a0]);
    gl16(Qhb + g1 + d0, &qh_s[a1]);
    gl16(Qlb + g0 + d0, &ql_s[a0]);
    gl16(Qlb + g1 + d0, &ql_s[a1]);
    gl16(Khb + g0 + d0, &kh_s[a0]);
    gl16(Khb + g1 + d0, &kh_s[a1]);
    gl16(Klb + g0 + d0, &kl_s[a0]);
    gl16(Klb + g1 + d0, &kl_s[a1]);
    __syncthreads();   // drains vmcnt for global_load_lds

    bf16x8 ah[4], al[4], bh[4], bl[4];
#pragma unroll
    for (int mt = 0; mt < 4; mt++) {
      int a = swz(wk0 + mt * 16 + lr, lq);
      ah[mt] = *(const bf16x8*)&qh_s[a];
      al[mt] = *(const bf16x8*)&ql_s[a];
    }
#pragma unroll
    for (int nt = 0; nt < 4; nt++) {
      int a = swz(wl0 + nt * 16 + lr, lq);
      bh[nt] = *(const bf16x8*)&kh_s[a];
      bl[nt] = *(const bf16x8*)&kl_s[a];
    }
#pragma unroll
    for (int mt = 0; mt < 4; mt++)
#pragma unroll
      for (int nt = 0; nt < 4; nt++) {
        acc[mt][nt] = __builtin_amdgcn_mfma_f32_16x16x32_bf16(ah[mt], bh[nt], acc[mt][nt], 0, 0, 0);
        acc[mt][nt] = __builtin_amdgcn_mfma_f32_16x16x32_bf16(ah[mt], bl[nt], acc[mt][nt], 0, 0, 0);
        acc[mt][nt] = __builtin_amdgcn_mfma_f32_16x16x32_bf16(al[mt], bh[nt], acc[mt][nt], 0, 0, 0);
      }
    __syncthreads();
  }

#pragma unroll
  for (int mt = 0; mt < 4; mt++)
#pragma unroll
    for (int nt = 0; nt < 4; nt++)
#pragma unroll
      for (int r = 0; r < 4; r++) {
        int k = k0 + wk0 + mt * 16 + lq * 4 + r;
        int l = l0 + wl0 + nt * 16 + lr;
        float s = acc[mt][nt][r] * SCALE_;
        if (causal && (l < k || s == 0.0f)) s = NEG_BIG_;  // faithful triu + zero->mask
        Sb[(size_t)k * W_ + l] = s;
      }
}

// ---- per-row softmax stats: m = max, inv = 1/sum(exp(s-m)) ----
__global__ __launch_bounds__(256) void softmax_stats_kernel(
    const float* __restrict__ S, float* __restrict__ mrow, float* __restrict__ invrow) {
  int row = blockIdx.x;  // 0 .. B_*W_-1
  const float* Sr = S + (size_t)row * W_;
  int t = threadIdx.x;
  float v[8];
  *(float4*)&v[0] = *(const float4*)&Sr[t * 8];
  *(float4*)&v[4] = *(const float4*)&Sr[t * 8 + 4];
  float mx = -INFINITY;
#pragma unroll
  for (int r = 0; r < 8; r++) mx = fmaxf(mx, v[r]);
#pragma unroll
  for (int off = 1; off < 64; off <<= 1) mx = fmaxf(mx, __shfl_xor(mx, off, 64));
  __shared__ float redm[4];
  __shared__ float reds[4];
  int wid = t >> 6, lane = t & 63;
  if (lane == 0) redm[wid] = mx;
  __syncthreads();
  mx = fmaxf(fmaxf(redm[0], redm[1]), fmaxf(redm[2], redm[3]));
  float sum = 0.f;
#pragma unroll
  for (int r = 0; r < 8; r++) sum += __expf(v[r] - mx);
#pragma unroll
  for (int off = 1; off < 64; off <<= 1) sum += __shfl_xor(sum, off, 64);
  if (lane == 0) reds[wid] = sum;
  __syncthreads();
  if (t == 0) {
    float s = reds[0] + reds[1] + reds[2] + reds[3];
    mrow[row] = mx;
    invrow[row] = 1.0f / s;
  }
}

// ---- out: O[d][k] = sum_l V[d][l] * P[k][l], P = exp(S-m)*inv (split bf16) ----
// Block = (b, k0-tile of 128, d-half of 256). 512 threads = 8 waves of 64d x 64k.
// P tile [128][32] computed ONCE per block in LDS (was 4x redundant).
// 2-deep pipeline, one barrier per chunk, V+P double-buffered (96 KB LDS).
// XCD-chunk swizzle: the two d-halves of one (b,k0) land on the same XCD ->
// their identical S-row reads hit L2.
__global__ __launch_bounds__(512) void out_fused(
    const unsigned short* __restrict__ Vhi, const unsigned short* __restrict__ Vlo,
    const float* __restrict__ S,
    const float* __restrict__ mrow, const float* __restrict__ invrow,
    float* __restrict__ O, const int* __restrict__ causal_p) {
  // flat dispatch id: grid = (32,1,8) -> f = z*32 + x; nwg = 256, divisible by 8.
  int f = blockIdx.z * 32 + blockIdx.x;
  int lf = (f & 7) * 32 + (f >> 3);    // XCD j owns logical [j*32,(j+1)*32)
  int b = lf >> 5;
  int r5 = lf & 31;
  int k0 = (r5 >> 1) * 128;
  int dh = r5 & 1;                     // d-half: rows [dh*256, dh*256+256)
  int causal = *causal_p;
  int t = threadIdx.x;
  int wave = t >> 6, lane = t & 63;
  int wd0 = (wave >> 1) * 64;          // 0,64,128,192 within the 256-d half
  int wk0 = (wave & 1) * 64;           // 0,64 within the 128-k tile
  int lr = lane & 15, lq = lane >> 4;

  __shared__ __align__(16) unsigned short vh_s[2][256 * 32], vl_s[2][256 * 32];  // 64 KB
  __shared__ __align__(16) unsigned short ph_s[2][128 * 32], pl_s[2][128 * 32];  // 32 KB

  const unsigned short* Vhb = Vhi + ((size_t)b * D_ + dh * 256) * W_;
  const unsigned short* Vlb = Vlo + ((size_t)b * D_ + dh * 256) * W_;
  const float* Sb = S + (size_t)b * W_ * W_;

  // V staging: 1024 slots = 256 rows x 4 chunks; thread owns slots t, t+512.
  // f(row) is invariant under row+128 ((row>>1)&3: +64 == 0 mod 4) -> same XOR.
  int vrow0 = t >> 2, vc = t & 3;
  int vxor = (vc ^ ((vrow0 >> 1) & 3)) << 3;
  const unsigned short* VhA = Vhb + (size_t)vrow0 * W_ + vxor;
  const unsigned short* VhB = VhA + (size_t)128 * W_;
  const unsigned short* VlA = Vlb + (size_t)vrow0 * W_ + vxor;
  const unsigned short* VlB = VlA + (size_t)128 * W_;
  int a0 = t * 8, a1 = t * 8 + 4096;   // linear LDS dest (shorts)

  // P staging: 512 slots = 128 rows x 4 chunks; thread owns one slot.
  int prow = t >> 2, pc = t & 3;
  const float* Srow = Sb + (size_t)(k0 + prow) * W_ + pc * 8;  // natural S read
  int paddr = prow * 32 + ((pc ^ ((prow >> 1) & 3)) << 3);     // swizzled P write
  float m = mrow[(size_t)b * W_ + k0 + prow];
  float inv = invrow[(size_t)b * W_ + k0 + prow];

  f32x4 acc[4][4];
#pragma unroll
  for (int i = 0; i < 4; i++)
#pragma unroll
    for (int j = 0; j < 4; j++) acc[i][j] = (f32x4){0.f, 0.f, 0.f, 0.f};

  int lstart = causal ? k0 : 0;        // P[k][l]=0 for l<k (S holds NEG_BIG there)
  int nch = (W_ - lstart) >> 5;

  float4 s0_, s1_;
  auto stageV = [&](int buf, int l) {
    gl16(VhA + l, &vh_s[buf][a0]);
    gl16(VhB + l, &vh_s[buf][a1]);
    gl16(VlA + l, &vl_s[buf][a0]);
    gl16(VlB + l, &vl_s[buf][a1]);
  };
  auto loadS = [&](int l) {
    s0_ = *(const float4*)&Srow[l];
    s1_ = *(const float4*)&Srow[l + 4];
  };
  auto writeP = [&](int buf) {
    float p[8];
    p[0] = __expf(s0_.x - m) * inv; p[1] = __expf(s0_.y - m) * inv;
    p[2] = __expf(s0_.z - m) * inv; p[3] = __expf(s0_.w - m) * inv;
    p[4] = __expf(s1_.x - m) * inv; p[5] = __expf(s1_.y - m) * inv;
    p[6] = __expf(s1_.z - m) * inv; p[7] = __expf(s1_.w - m) * inv;
    unsigned short hi8[8] __attribute__((aligned(16)));
    unsigned short lo8[8] __attribute__((aligned(16)));
#pragma unroll
    for (int j = 0; j < 8; j++) split2(p[j], hi8[j], lo8[j]);
    *(uint4*)&ph_s[buf][paddr] = *(uint4*)hi8;
    *(uint4*)&pl_s[buf][paddr] = *(uint4*)lo8;
  };

  // prologue: chunk 0 into buf 0
  stageV(0, lstart);
  loadS(lstart);
  writeP(0);
  __syncthreads();

  for (int ci = 0; ci < nch; ci++) {
    int cur = ci & 1, nxt = cur ^ 1;
    bool pre = (ci + 1 < nch);
    if (pre) {                 // issue next chunk's V-DMA + S register loads early
      int ln = lstart + (ci + 1) * 32;
      stageV(nxt, ln);
      loadS(ln);
    }

    bf16x8 ah[4], al[4], bh[4], bl[4];
#pragma unroll
    for (int mt = 0; mt < 4; mt++) {
      int a = swz(wd0 + mt * 16 + lr, lq);
      ah[mt] = *(const bf16x8*)&vh_s[cur][a];
      al[mt] = *(const bf16x8*)&vl_s[cur][a];
    }
#pragma unroll
    for (int nt = 0; nt < 4; nt++) {
      int a = swz(wk0 + nt * 16 + lr, lq);
      bh[nt] = *(const bf16x8*)&ph_s[cur][a];
      bl[nt] = *(const bf16x8*)&pl_s[cur][a];
    }
#pragma unroll
    for (int mt = 0; mt < 4; mt++)
#pragma unroll
      for (int nt = 0; nt < 4; nt++) {
        acc[mt][nt] = __builtin_amdgcn_mfma_f32_16x16x32_bf16(ah[mt], bh[nt], acc[mt][nt], 0, 0, 0);
        acc[mt][nt] = __builtin_amdgcn_mfma_f32_16x16x32_bf16(ah[mt], bl[nt], acc[mt][nt], 0, 0, 0);
        acc[mt][nt] = __builtin_amdgcn_mfma_f32_16x16x32_bf16(al[mt], bh[nt], acc[mt][nt], 0, 0, 0);
      }

    if (pre) writeP(nxt);      // exp/split + ds_write into the OTHER buffer
    __syncthreads();           // one barrier per chunk (drains vmcnt + lgkm)
  }

#pragma unroll
  for (int mt = 0; mt < 4; mt++)
#pragma unroll
    for (int nt = 0; nt < 4; nt++)
#pragma unroll
      for (int r = 0; r < 4; r++) {
        int d = dh * 256 + wd0 + mt * 16 + lq * 4 + r;
        int k = k0 + wk0 + nt * 16 + lr;
        O[((size_t)b * D_ + d) * W_ + k] = acc[mt][nt][r];
      }
}

extern "C" void kernel_launch(void* const* d_in, const int* in_sizes, int n_in,
                              void* d_out, int out_size, void* d_ws, size_t ws_size,
                              hipStream_t stream) {
  const float* x  = (const float*)d_in[0];
  const float* Wq = (const float*)d_in[1];
  const float* bq = (const float*)d_in[2];
  const float* Wk = (const float*)d_in[3];
  const float* bk = (const float*)d_in[4];
  const float* Wv = (const float*)d_in[5];
  const float* bv = (const float*)d_in[6];
  const int* causal = (const int*)d_in[7];

  float* out = (float*)d_out;
  float* x_out = out;                                   // 8*512*2048
  float* S = out + (size_t)B_ * D_ * W_;                // 8*2048*2048

  const size_t NQ = (size_t)B_ * W_ * D_;               // 8,388,608
  unsigned short* wsu = (unsigned short*)d_ws;
  unsigned short* Qhi = wsu;
  unsigned short* Qlo = wsu + NQ;
  unsigned short* Khi = wsu + 2 * NQ;
  unsigned short* Klo = wsu + 3 * NQ;
  unsigned short* Vhi = wsu + 4 * NQ;
  unsigned short* Vlo = wsu + 5 * NQ;
  float* mrow   = (float*)(wsu + 6 * NQ);               // B_*W_ = 16384
  float* invrow = mrow + (size_t)B_ * W_;

  int nproj = (int)(NQ / 256);
  proj_qk<<<nproj, 256, 0, stream>>>(x, Wq, bq, Wk, bk, Qhi, Qlo, Khi, Klo);
  proj_v<<<nproj, 256, 0, stream>>>(x, Wv, bv, Vhi, Vlo);
  scores_mfma<<<dim3(W_ / 128, W_ / 128, B_), 256, 0, stream>>>(Qhi, Qlo, Khi, Klo, S, causal);
  softmax_stats_kernel<<<B_ * W_, 256, 0, stream>>>(S, mrow, invrow);
  out_fused<<<dim3(32, 1, B_), 512, 0, stream>>>(Vhi, Vlo, S, mrow, invrow, x_out, causal);
}

// Round 3
// 416.925 us; speedup vs baseline: 1.1348x; 1.0413x over previous
//
#include <hip/hip_runtime.h>
#include <math.h>

// attention_block: B=8, C_IN=4, C_OUT=64, H=8, W=2048, d=C_OUT*H=512
// out = [x_out (8*512*2048) fp32] ++ [masked pre-softmax scores (8*2048*2048) fp32]
//
// R8: kill out_fused's per-chunk latency stall. R7 post-mortem: P-sharing
// worked (FETCH -54%, VALU -30%) but dur only -13% -> stall = writeP waiting
// ~900cyc on S loads issued the same chunk (vmcnt drains V DMA too), at
// 1 block/CU with no inter-block hiding. Fix: S prefetch distance 2 (named
// even/odd float4 register sets, explicit 2x-unrolled loop - no runtime reg
// indexing), writeP moved BEFORE the MFMA cluster (barrier-drain guarantees
// its S arrived last chunk -> zero wait), V DMA gets full chunk body to land.
// T5 setprio around MFMA. softmax_stats skips loading fully-masked chunks
// (bit-identical: masked entries are NEG_BIG, contribute exp(-huge)=0).
// scores_mfma: setprio only (multi-block implicit-overlap regime, m99/m100).
//
// ws layout unchanged (~100.8 MB):
//   Qhi,Qlo,Khi,Klo: [b][w][d] bf16; Vhi,Vlo: [b][d][w] bf16; mrow,invrow: [b*W] f32

#define B_ 8
#define W_ 2048
#define D_ 512
#define SCALE_ 0.04419417382415922f  // 1/sqrt(512)
#define NEG_BIG_ (-3.0e38f)

typedef __attribute__((ext_vector_type(8))) short bf16x8;
typedef __attribute__((ext_vector_type(4))) float f32x4;

__device__ __forceinline__ unsigned short f2bf(float x) {  // RNE truncate f32->bf16
  unsigned int u = __float_as_uint(x);
  u += 0x7fffu + ((u >> 16) & 1u);
  return (unsigned short)(u >> 16);
}
__device__ __forceinline__ float bf2f(unsigned short h) {
  return __uint_as_float(((unsigned int)h) << 16);
}
__device__ __forceinline__ void split2(float x, unsigned short& hi, unsigned short& lo) {
  hi = f2bf(x);
  lo = f2bf(x - bf2f(hi));
}

// async global->LDS, 16B per lane (dest = wave-uniform base + lane*16 pattern).
__device__ __forceinline__ void gl16(const unsigned short* g, unsigned short* l) {
  __builtin_amdgcn_global_load_lds(
      (__attribute__((address_space(1))) void*)const_cast<unsigned short*>(g),
      (__attribute__((address_space(3))) void*)l, 16, 0, 0);
}

// swizzled fragment address in a [R][32]-short tile: row*64B + (lq^f(row))*16B.
// f(row)=(row>>1)&3: conflict-free b128 column reads (verified R6: conflicts=0).
__device__ __forceinline__ int swz(int row, int lq) {
  return row * 32 + ((lq ^ ((row >> 1) & 3)) << 3);
}

// ---- projection: q,k with d-fastest indexing -> Q~,K~ [b][w][d] coalesced ----
__global__ __launch_bounds__(256) void proj_qk(
    const float* __restrict__ x,
    const float* __restrict__ Wq, const float* __restrict__ bq,
    const float* __restrict__ Wk, const float* __restrict__ bk,
    unsigned short* __restrict__ Qhi, unsigned short* __restrict__ Qlo,
    unsigned short* __restrict__ Khi, unsigned short* __restrict__ Klo) {
  int idx = blockIdx.x * 256 + threadIdx.x;   // (b, w, d) d-fastest
  int d = idx & (D_ - 1);
  int w = (idx >> 9) & (W_ - 1);
  int b = idx >> 20;
  int o = d >> 3, h = d & 7;
  const float* xp = x + (((size_t)b * 4) * 8 + h) * W_ + w;   // c-stride 8*W_
  float x0 = xp[0], x1 = xp[8 * W_], x2 = xp[16 * W_], x3 = xp[24 * W_];
  const float* wq = Wq + o * 4;
  const float* wk = Wk + o * 4;
  float q = bq[o] + wq[0] * x0 + wq[1] * x1 + wq[2] * x2 + wq[3] * x3;
  float k = bk[o] + wk[0] * x0 + wk[1] * x1 + wk[2] * x2 + wk[3] * x3;
  unsigned short h16, l16;
  split2(q, h16, l16); Qhi[idx] = h16; Qlo[idx] = l16;
  split2(k, h16, l16); Khi[idx] = h16; Klo[idx] = l16;
}

// ---- projection: v with w-fastest indexing -> V [b][d][w] coalesced ----
__global__ __launch_bounds__(256) void proj_v(
    const float* __restrict__ x,
    const float* __restrict__ Wv, const float* __restrict__ bv,
    unsigned short* __restrict__ Vhi, unsigned short* __restrict__ Vlo) {
  int idx = blockIdx.x * 256 + threadIdx.x;   // (b, d, w) w-fastest
  int w = idx & (W_ - 1);
  int rest = idx >> 11;
  int d = rest & (D_ - 1);
  int b = rest >> 9;
  int o = d >> 3, h = d & 7;
  const float* xp = x + (((size_t)b * 4) * 8 + h) * W_ + w;
  float x0 = xp[0], x1 = xp[8 * W_], x2 = xp[16 * W_], x3 = xp[24 * W_];
  const float* wv = Wv + o * 4;
  float v = bv[o] + wv[0] * x0 + wv[1] * x1 + wv[2] * x2 + wv[3] * x3;
  unsigned short h16, l16;
  split2(v, h16, l16); Vhi[idx] = h16; Vlo[idx] = l16;
}

// ---- scores: S[k][l] = sum_d Q~[k][d]*K~[l][d] * SCALE, causal mask ----
// 128x128 block tile, 4 waves of 64x64, 16x16x32 bf16 MFMA, split-precision.
// XCD-chunk swizzle: per-XCD logical chunk of 256 blocks = one b's tile grid.
__global__ __launch_bounds__(256) void scores_mfma(
    const unsigned short* __restrict__ Qhi, const unsigned short* __restrict__ Qlo,
    const unsigned short* __restrict__ Khi, const unsigned short* __restrict__ Klo,
    float* __restrict__ S, const int* __restrict__ causal_p) {
  // flat dispatch id (x fastest); nwg = 2048, divisible by 8.
  int f = (blockIdx.z * 16 + blockIdx.y) * 16 + blockIdx.x;
  int lf = (f & 7) * 256 + (f >> 3);   // XCD j owns logical [j*256,(j+1)*256)
  int b = lf >> 8;
  int k0 = ((lf >> 4) & 15) * 128;
  int l0 = (lf & 15) * 128;
  int causal = *causal_p;
  int t = threadIdx.x;
  float* Sb = S + (size_t)b * W_ * W_;

  if (causal && (l0 + 127 < k0)) {   // tile fully below diagonal
    float4 nb = make_float4(NEG_BIG_, NEG_BIG_, NEG_BIG_, NEG_BIG_);
    int row = t >> 1, c0 = (t & 1) * 64;
#pragma unroll
    for (int j = 0; j < 16; j++)
      *(float4*)&Sb[(size_t)(k0 + row) * W_ + l0 + c0 + j * 4] = nb;
    return;
  }

  __shared__ __align__(16) unsigned short qh_s[128 * 32], ql_s[128 * 32];
  __shared__ __align__(16) unsigned short kh_s[128 * 32], kl_s[128 * 32];

  int wave = t >> 6, lane = t & 63;
  int wk0 = (wave >> 1) * 64, wl0 = (wave & 1) * 64;
  int lr = lane & 15, lq = lane >> 4;

  const unsigned short* Qhb = Qhi + ((size_t)b * W_ + k0) * D_;
  const unsigned short* Qlb = Qlo + ((size_t)b * W_ + k0) * D_;
  const unsigned short* Khb = Khi + ((size_t)b * W_ + l0) * D_;
  const unsigned short* Klb = Klo + ((size_t)b * W_ + l0) * D_;

  // staging: 512 slots = 128 rows x 4 chunks; thread owns slots t, t+256.
  // Global source chunk-permuted; LDS dest linear.
  int srow0 = t >> 2, sq = t & 3;
  int srow1 = srow0 + 64;
  size_t g0 = (size_t)srow0 * D_ + ((sq ^ ((srow0 >> 1) & 3)) << 3);
  size_t g1 = (size_t)srow1 * D_ + ((sq ^ ((srow1 >> 1) & 3)) << 3);
  int a0 = t * 8, a1 = t * 8 + 2048;   // shorts

  f32x4 acc[4][4];
#pragma unroll
  for (int i = 0; i < 4; i++)
#pragma unroll
    for (int j = 0; j < 4; j++) acc[i][j] = (f32x4){0.f, 0.f, 0.f, 0.f};

  for (int d0 = 0; d0 < D_; d0 += 32) {
    gl16(Qhb + g0 + d0, &qh_s[a0]);
    gl16(Qhb + g1 + d0, &qh_s[a1]);
    gl16(Qlb + g0 + d0, &ql_s[a0]);
    gl16(Qlb + g1 + d0, &ql_s[a1]);
    gl16(Khb + g0 + d0, &kh_s[a0]);
    gl16(Khb + g1 + d0, &kh_s[a1]);
    gl16(Klb + g0 + d0, &kl_s[a0]);
    gl16(Klb + g1 + d0, &kl_s[a1]);
    __syncthreads();   // drains vmcnt for global_load_lds

    bf16x8 ah[4], al[4], bh[4], bl[4];
#pragma unroll
    for (int mt = 0; mt < 4; mt++) {
      int a = swz(wk0 + mt * 16 + lr, lq);
      ah[mt] = *(const bf16x8*)&qh_s[a];
      al[mt] = *(const bf16x8*)&ql_s[a];
    }
#pragma unroll
    for (int nt = 0; nt < 4; nt++) {
      int a = swz(wl0 + nt * 16 + lr, lq);
      bh[nt] = *(const bf16x8*)&kh_s[a];
      bl[nt] = *(const bf16x8*)&kl_s[a];
    }
    __builtin_amdgcn_s_setprio(1);
#pragma unroll
    for (int mt = 0; mt < 4; mt++)
#pragma unroll
      for (int nt = 0; nt < 4; nt++) {
        acc[mt][nt] = __builtin_amdgcn_mfma_f32_16x16x32_bf16(ah[mt], bh[nt], acc[mt][nt], 0, 0, 0);
        acc[mt][nt] = __builtin_amdgcn_mfma_f32_16x16x32_bf16(ah[mt], bl[nt], acc[mt][nt], 0, 0, 0);
        acc[mt][nt] = __builtin_amdgcn_mfma_f32_16x16x32_bf16(al[mt], bh[nt], acc[mt][nt], 0, 0, 0);
      }
    __builtin_amdgcn_s_setprio(0);
    __syncthreads();
  }

#pragma unroll
  for (int mt = 0; mt < 4; mt++)
#pragma unroll
    for (int nt = 0; nt < 4; nt++)
#pragma unroll
      for (int r = 0; r < 4; r++) {
        int k = k0 + wk0 + mt * 16 + lq * 4 + r;
        int l = l0 + wl0 + nt * 16 + lr;
        float s = acc[mt][nt][r] * SCALE_;
        if (causal && (l < k || s == 0.0f)) s = NEG_BIG_;  // faithful triu + zero->mask
        Sb[(size_t)k * W_ + l] = s;
      }
}

// ---- per-row softmax stats: m = max, inv = 1/sum(exp(s-m)) ----
// Causal skip: chunks fully below the diagonal hold NEG_BIG (written by
// scores_mfma) - substitute the constant instead of loading. Bit-identical:
// those entries never win the max (valid diagonal exists) and exp(-huge)=0.
__global__ __launch_bounds__(256) void softmax_stats_kernel(
    const float* __restrict__ S, float* __restrict__ mrow, float* __restrict__ invrow,
    const int* __restrict__ causal_p) {
  int row = blockIdx.x;  // 0 .. B_*W_-1
  int k = row & (W_ - 1);
  int causal = *causal_p;
  const float* Sr = S + (size_t)row * W_;
  int t = threadIdx.x;
  float v[8];
  if (causal && (t * 8 + 8 <= k)) {
#pragma unroll
    for (int r = 0; r < 8; r++) v[r] = NEG_BIG_;
  } else {
    *(float4*)&v[0] = *(const float4*)&Sr[t * 8];
    *(float4*)&v[4] = *(const float4*)&Sr[t * 8 + 4];
  }
  float mx = -INFINITY;
#pragma unroll
  for (int r = 0; r < 8; r++) mx = fmaxf(mx, v[r]);
#pragma unroll
  for (int off = 1; off < 64; off <<= 1) mx = fmaxf(mx, __shfl_xor(mx, off, 64));
  __shared__ float redm[4];
  __shared__ float reds[4];
  int wid = t >> 6, lane = t & 63;
  if (lane == 0) redm[wid] = mx;
  __syncthreads();
  mx = fmaxf(fmaxf(redm[0], redm[1]), fmaxf(redm[2], redm[3]));
  float sum = 0.f;
#pragma unroll
  for (int r = 0; r < 8; r++) sum += __expf(v[r] - mx);
#pragma unroll
  for (int off = 1; off < 64; off <<= 1) sum += __shfl_xor(sum, off, 64);
  if (lane == 0) reds[wid] = sum;
  __syncthreads();
  if (t == 0) {
    float s = reds[0] + reds[1] + reds[2] + reds[3];
    mrow[row] = mx;
    invrow[row] = 1.0f / s;
  }
}

// ---- out: O[d][k] = sum_l V[d][l] * P[k][l], P = exp(S-m)*inv (split bf16) ----
// Block = (b, k0-tile of 128, d-half of 256). 512 threads = 8 waves of 64d x 64k.
// Pipeline: S prefetch distance 2 (even/odd named reg sets), writeP BEFORE the
// MFMA cluster (its S arrived last chunk; barrier drain guarantees it), V DMA
// prefetch 1 (dbuf) gets the full chunk body to cover HBM latency. One barrier
// per chunk. nch is always a multiple of 4 -> exact even/odd pairs.
__global__ __launch_bounds__(512) void out_fused(
    const unsigned short* __restrict__ Vhi, const unsigned short* __restrict__ Vlo,
    const float* __restrict__ S,
    const float* __restrict__ mrow, const float* __restrict__ invrow,
    float* __restrict__ O, const int* __restrict__ causal_p) {
  // flat dispatch id: grid = (32,1,8) -> f = z*32 + x; nwg = 256, divisible by 8.
  int f = blockIdx.z * 32 + blockIdx.x;
  int lf = (f & 7) * 32 + (f >> 3);    // XCD j owns logical [j*32,(j+1)*32)
  int b = lf >> 5;
  int r5 = lf & 31;
  int k0 = (r5 >> 1) * 128;
  int dh = r5 & 1;                     // d-half: rows [dh*256, dh*256+256)
  int causal = *causal_p;
  int t = threadIdx.x;
  int wave = t >> 6, lane = t & 63;
  int wd0 = (wave >> 1) * 64;          // 0,64,128,192 within the 256-d half
  int wk0 = (wave & 1) * 64;           // 0,64 within the 128-k tile
  int lr = lane & 15, lq = lane >> 4;

  __shared__ __align__(16) unsigned short vh_s[2][256 * 32], vl_s[2][256 * 32];  // 64 KB
  __shared__ __align__(16) unsigned short ph_s[2][128 * 32], pl_s[2][128 * 32];  // 32 KB

  const unsigned short* Vhb = Vhi + ((size_t)b * D_ + dh * 256) * W_;
  const unsigned short* Vlb = Vlo + ((size_t)b * D_ + dh * 256) * W_;
  const float* Sb = S + (size_t)b * W_ * W_;

  // V staging: 1024 slots = 256 rows x 4 chunks; thread owns slots t, t+512.
  int vrow0 = t >> 2, vc = t & 3;
  int vxor = (vc ^ ((vrow0 >> 1) & 3)) << 3;
  const unsigned short* VhA = Vhb + (size_t)vrow0 * W_ + vxor;
  const unsigned short* VhB = VhA + (size_t)128 * W_;
  const unsigned short* VlA = Vlb + (size_t)vrow0 * W_ + vxor;
  const unsigned short* VlB = VlA + (size_t)128 * W_;
  int a0 = t * 8, a1 = t * 8 + 4096;   // linear LDS dest (shorts)

  // P staging: 512 slots = 128 rows x 4 chunks; thread owns one slot.
  int prow = t >> 2, pc = t & 3;
  const float* Srow = Sb + (size_t)(k0 + prow) * W_ + pc * 8;  // natural S read
  int paddr = prow * 32 + ((pc ^ ((prow >> 1) & 3)) << 3);     // swizzled P write
  float m = mrow[(size_t)b * W_ + k0 + prow];
  float inv = invrow[(size_t)b * W_ + k0 + prow];

  f32x4 acc[4][4];
#pragma unroll
  for (int i = 0; i < 4; i++)
#pragma unroll
    for (int j = 0; j < 4; j++) acc[i][j] = (f32x4){0.f, 0.f, 0.f, 0.f};

  int lstart = causal ? k0 : 0;        // P[k][l]=0 for l<k (S holds NEG_BIG there)
  int nch = (W_ - lstart) >> 5;        // multiple of 4

  auto stageV = [&](int buf, int l) {
    gl16(VhA + l, &vh_s[buf][a0]);
    gl16(VhB + l, &vh_s[buf][a1]);
    gl16(VlA + l, &vl_s[buf][a0]);
    gl16(VlB + l, &vl_s[buf][a1]);
  };
  auto writeP = [&](unsigned short* __restrict__ ph, unsigned short* __restrict__ pl,
                    float4 s0, float4 s1) {
    float p[8];
    p[0] = __expf(s0.x - m) * inv; p[1] = __expf(s0.y - m) * inv;
    p[2] = __expf(s0.z - m) * inv; p[3] = __expf(s0.w - m) * inv;
    p[4] = __expf(s1.x - m) * inv; p[5] = __expf(s1.y - m) * inv;
    p[6] = __expf(s1.z - m) * inv; p[7] = __expf(s1.w - m) * inv;
    unsigned short hi8[8] __attribute__((aligned(16)));
    unsigned short lo8[8] __attribute__((aligned(16)));
#pragma unroll
    for (int j = 0; j < 8; j++) split2(p[j], hi8[j], lo8[j]);
    *(uint4*)&ph[paddr] = *(uint4*)hi8;
    *(uint4*)&pl[paddr] = *(uint4*)lo8;
  };
  auto compute = [&](const unsigned short* vh, const unsigned short* vl,
                     const unsigned short* ph, const unsigned short* pl) {
    bf16x8 ah[4], al[4], bh[4], bl[4];
#pragma unroll
    for (int mt = 0; mt < 4; mt++) {
      int a = swz(wd0 + mt * 16 + lr, lq);
      ah[mt] = *(const bf16x8*)&vh[a];
      al[mt] = *(const bf16x8*)&vl[a];
    }
#pragma unroll
    for (int nt = 0; nt < 4; nt++) {
      int a = swz(wk0 + nt * 16 + lr, lq);
      bh[nt] = *(const bf16x8*)&ph[a];
      bl[nt] = *(const bf16x8*)&pl[a];
    }
    __builtin_amdgcn_s_setprio(1);
#pragma unroll
    for (int mt = 0; mt < 4; mt++)
#pragma unroll
      for (int nt = 0; nt < 4; nt++) {
        acc[mt][nt] = __builtin_amdgcn_mfma_f32_16x16x32_bf16(ah[mt], bh[nt], acc[mt][nt], 0, 0, 0);
        acc[mt][nt] = __builtin_amdgcn_mfma_f32_16x16x32_bf16(ah[mt], bl[nt], acc[mt][nt], 0, 0, 0);
        acc[mt][nt] = __builtin_amdgcn_mfma_f32_16x16x32_bf16(al[mt], bh[nt], acc[mt][nt], 0, 0, 0);
      }
    __builtin_amdgcn_s_setprio(0);
  };

  // S registers: even/odd chunk sets (named, no runtime indexing).
  float4 sE0, sE1, sO0, sO1;

  // prologue: S(0),S(1) in regs; V(0) DMA; P(0) written (waits S(0) once).
  sE0 = *(const float4*)&Srow[lstart];      sE1 = *(const float4*)&Srow[lstart + 4];
  sO0 = *(const float4*)&Srow[lstart + 32]; sO1 = *(const float4*)&Srow[lstart + 36];
  stageV(0, lstart);
  writeP(&ph_s[0][0], &pl_s[0][0], sE0, sE1);
  __syncthreads();

  for (int ci = 0; ci < nch; ci += 2) {
    int base = lstart + ci * 32;
    // ---- even chunk ci: consumes vbuf0/pbuf0 ----
    if (ci + 2 < nch) {                // S(ci+2) -> E set (E was consumed last chunk)
      sE0 = *(const float4*)&Srow[base + 64];
      sE1 = *(const float4*)&Srow[base + 68];
    }
    stageV(1, base + 32);              // V(ci+1) DMA (lands during this chunk)
    writeP(&ph_s[1][0], &pl_s[1][0], sO0, sO1);   // P(ci+1); S(ci+1) already arrived
    compute(&vh_s[0][0], &vl_s[0][0], &ph_s[0][0], &pl_s[0][0]);
    __syncthreads();
    // ---- odd chunk ci+1: consumes vbuf1/pbuf1 ----
    bool more = (ci + 2 < nch);
    if (ci + 3 < nch) {                // S(ci+3) -> O set
      sO0 = *(const float4*)&Srow[base + 96];
      sO1 = *(const float4*)&Srow[base + 100];
    }
    if (more) {
      stageV(0, base + 64);            // V(ci+2) DMA
      writeP(&ph_s[0][0], &pl_s[0][0], sE0, sE1); // P(ci+2); S(ci+2) arrived
    }
    compute(&vh_s[1][0], &vl_s[1][0], &ph_s[1][0], &pl_s[1][0]);
    __syncthreads();
  }

#pragma unroll
  for (int mt = 0; mt < 4; mt++)
#pragma unroll
    for (int nt = 0; nt < 4; nt++)
#pragma unroll
      for (int r = 0; r < 4; r++) {
        int d = dh * 256 + wd0 + mt * 16 + lq * 4 + r;
        int k = k0 + wk0 + nt * 16 + lr;
        O[((size_t)b * D_ + d) * W_ + k] = acc[mt][nt][r];
      }
}

extern "C" void kernel_launch(void* const* d_in, const int* in_sizes, int n_in,
                              void* d_out, int out_size, void* d_ws, size_t ws_size,
                              hipStream_t stream) {
  const float* x  = (const float*)d_in[0];
  const float* Wq = (const float*)d_in[1];
  const float* bq = (const float*)d_in[2];
  const float* Wk = (const float*)d_in[3];
  const float* bk = (const float*)d_in[4];
  const float* Wv = (const float*)d_in[5];
  const float* bv = (const float*)d_in[6];
  const int* causal = (const int*)d_in[7];

  float* out = (float*)d_out;
  float* x_out = out;                                   // 8*512*2048
  float* S = out + (size_t)B_ * D_ * W_;                // 8*2048*2048

  const size_t NQ = (size_t)B_ * W_ * D_;               // 8,388,608
  unsigned short* wsu = (unsigned short*)d_ws;
  unsigned short* Qhi = wsu;
  unsigned short* Qlo = wsu + NQ;
  unsigned short* Khi = wsu + 2 * NQ;
  unsigned short* Klo = wsu + 3 * NQ;
  unsigned short* Vhi = wsu + 4 * NQ;
  unsigned short* Vlo = wsu + 5 * NQ;
  float* mrow   = (float*)(wsu + 6 * NQ);               // B_*W_ = 16384
  float* invrow = mrow + (size_t)B_ * W_;

  int nproj = (int)(NQ / 256);
  proj_qk<<<nproj, 256, 0, stream>>>(x, Wq, bq, Wk, bk, Qhi, Qlo, Khi, Klo);
  proj_v<<<nproj, 256, 0, stream>>>(x, Wv, bv, Vhi, Vlo);
  scores_mfma<<<dim3(W_ / 128, W_ / 128, B_), 256, 0, stream>>>(Qhi, Qlo, Khi, Klo, S, causal);
  softmax_stats_kernel<<<B_ * W_, 256, 0, stream>>>(S, mrow, invrow, causal);
  out_fused<<<dim3(32, 1, B_), 512, 0, stream>>>(Vhi, Vlo, S, mrow, invrow, x_out, causal);
}

// Round 4
// 370.112 us; speedup vs baseline: 1.2784x; 1.1265x over previous
//
#include <hip/hip_runtime.h>
#include <math.h>

// attention_block: B=8, C_IN=4, C_OUT=64, H=8, W=2048, d=C_OUT*H=512
// out = [x_out (8*512*2048) fp32] ++ [masked pre-softmax scores (8*2048*2048) fp32]
//
// R9: (1) out_bal: balanced grid (b,k0,dq) = 512 blocks x 256 thr, LPT dispatch
// order (k0 ascending = biggest jobs first) -> makespan ~68 chunks/CU vs R8's
// 64-chunk single-block tail at 1 block/CU. Same R8 pipeline (S dist-2, writeP
// before MFMA, V dbuf, 1 barrier/chunk, verified swizzle, setprio). 64 KB LDS
// -> 2 blocks/CU. (2) scores emits per-tile softmax stats (m_t, sum exp(v-m_t))
// in a cheap epilogue; combine_stats (2 MB read) replaces softmax_stats' ~64 MB
// S re-read. mrow bit-identical (max exact); invrow ~1ulp regrouping.
// (3) proj: 8 outputs/thread, uint4 stores (was 2B scalar stores).
//
// ws (~102.9 MB): Qhi,Qlo,Khi,Klo [b][w][d] bf16; Vhi,Vlo [b][d][w] bf16;
// mrow,invrow [b*W] f32; stats [b][W][16] float2 (per-l-tile m,s).

#define B_ 8
#define W_ 2048
#define D_ 512
#define SCALE_ 0.04419417382415922f  // 1/sqrt(512)
#define NEG_BIG_ (-3.0e38f)

typedef __attribute__((ext_vector_type(8))) short bf16x8;
typedef __attribute__((ext_vector_type(4))) float f32x4;

__device__ __forceinline__ unsigned short f2bf(float x) {  // RNE truncate f32->bf16
  unsigned int u = __float_as_uint(x);
  u += 0x7fffu + ((u >> 16) & 1u);
  return (unsigned short)(u >> 16);
}
__device__ __forceinline__ float bf2f(unsigned short h) {
  return __uint_as_float(((unsigned int)h) << 16);
}
__device__ __forceinline__ void split2(float x, unsigned short& hi, unsigned short& lo) {
  hi = f2bf(x);
  lo = f2bf(x - bf2f(hi));
}

// async global->LDS, 16B per lane (dest = wave-uniform base + lane*16 pattern).
__device__ __forceinline__ void gl16(const unsigned short* g, unsigned short* l) {
  __builtin_amdgcn_global_load_lds(
      (__attribute__((address_space(1))) void*)const_cast<unsigned short*>(g),
      (__attribute__((address_space(3))) void*)l, 16, 0, 0);
}

// swizzled fragment address in a [R][32]-short tile: row*64B + (lq^f(row))*16B.
// f(row)=(row>>1)&3: conflict-free b128 column reads (verified R6: conflicts=0).
__device__ __forceinline__ int swz(int row, int lq) {
  return row * 32 + ((lq ^ ((row >> 1) & 3)) << 3);
}

// ---- projection: q,k -> Q~,K~ [b][w][d]; thread = (b,w,o), 8 d-values ----
__global__ __launch_bounds__(256) void proj_qk(
    const float* __restrict__ x,
    const float* __restrict__ Wq, const float* __restrict__ bq,
    const float* __restrict__ Wk, const float* __restrict__ bk,
    unsigned short* __restrict__ Qhi, unsigned short* __restrict__ Qlo,
    unsigned short* __restrict__ Khi, unsigned short* __restrict__ Klo) {
  int idx = blockIdx.x * 256 + threadIdx.x;   // B*W*64
  int o = idx & 63;
  int w = (idx >> 6) & (W_ - 1);
  int b = idx >> 17;
  const float* xb = x + (size_t)b * 32 * W_ + w;   // x[b][c][h][w], c-stride 8W, h-stride W
  float xv[4][8];
#pragma unroll
  for (int c = 0; c < 4; c++)
#pragma unroll
    for (int h = 0; h < 8; h++) xv[c][h] = xb[(c * 8 + h) * W_];
  float wq0 = Wq[o * 4], wq1 = Wq[o * 4 + 1], wq2 = Wq[o * 4 + 2], wq3 = Wq[o * 4 + 3];
  float wk0 = Wk[o * 4], wk1 = Wk[o * 4 + 1], wk2 = Wk[o * 4 + 2], wk3 = Wk[o * 4 + 3];
  float bqv = bq[o], bkv = bk[o];
  unsigned short qh8[8] __attribute__((aligned(16))), ql8[8] __attribute__((aligned(16)));
  unsigned short kh8[8] __attribute__((aligned(16))), kl8[8] __attribute__((aligned(16)));
#pragma unroll
  for (int h = 0; h < 8; h++) {
    float q = bqv + wq0 * xv[0][h] + wq1 * xv[1][h] + wq2 * xv[2][h] + wq3 * xv[3][h];
    float k = bkv + wk0 * xv[0][h] + wk1 * xv[1][h] + wk2 * xv[2][h] + wk3 * xv[3][h];
    split2(q, qh8[h], ql8[h]);
    split2(k, kh8[h], kl8[h]);
  }
  size_t base = ((size_t)b * W_ + w) * D_ + o * 8;
  *(uint4*)&Qhi[base] = *(uint4*)qh8;
  *(uint4*)&Qlo[base] = *(uint4*)ql8;
  *(uint4*)&Khi[base] = *(uint4*)kh8;
  *(uint4*)&Klo[base] = *(uint4*)kl8;
}

// ---- projection: v -> V [b][d][w]; thread = (b,d,w-chunk of 8) ----
__global__ __launch_bounds__(256) void proj_v(
    const float* __restrict__ x,
    const float* __restrict__ Wv, const float* __restrict__ bv,
    unsigned short* __restrict__ Vhi, unsigned short* __restrict__ Vlo) {
  int idx = blockIdx.x * 256 + threadIdx.x;   // B*D*256
  int wc = idx & 255;
  int d = (idx >> 8) & (D_ - 1);
  int b = idx >> 17;
  int o = d >> 3, h = d & 7;
  const float* xp = x + ((size_t)(b * 4) * 8 + h) * W_ + wc * 8;
  float4 xa[4][2];
#pragma unroll
  for (int c = 0; c < 4; c++) {
    xa[c][0] = *(const float4*)&xp[(size_t)c * 8 * W_];
    xa[c][1] = *(const float4*)&xp[(size_t)c * 8 * W_ + 4];
  }
  float w0 = Wv[o * 4], w1 = Wv[o * 4 + 1], w2 = Wv[o * 4 + 2], w3 = Wv[o * 4 + 3];
  float bvv = bv[o];
  unsigned short vh8[8] __attribute__((aligned(16))), vl8[8] __attribute__((aligned(16)));
#pragma unroll
  for (int j = 0; j < 8; j++) {
    float x0 = (j < 4) ? ((const float*)&xa[0][0])[j] : ((const float*)&xa[0][1])[j - 4];
    float x1 = (j < 4) ? ((const float*)&xa[1][0])[j] : ((const float*)&xa[1][1])[j - 4];
    float x2 = (j < 4) ? ((const float*)&xa[2][0])[j] : ((const float*)&xa[2][1])[j - 4];
    float x3 = (j < 4) ? ((const float*)&xa[3][0])[j] : ((const float*)&xa[3][1])[j - 4];
    float v = bvv + w0 * x0 + w1 * x1 + w2 * x2 + w3 * x3;
    split2(v, vh8[j], vl8[j]);
  }
  size_t base = ((size_t)b * D_ + d) * W_ + wc * 8;
  *(uint4*)&Vhi[base] = *(uint4*)vh8;
  *(uint4*)&Vlo[base] = *(uint4*)vl8;
}

// ---- scores: S[k][l] = sum_d Q~[k][d]*K~[l][d] * SCALE, causal mask ----
// 128x128 block tile, 4 waves of 64x64, split-precision MFMA. Epilogue also
// emits per-tile softmax stats (m_t, sum exp(v-m_t)) per row -> ws stats.
__global__ __launch_bounds__(256) void scores_mfma(
    const unsigned short* __restrict__ Qhi, const unsigned short* __restrict__ Qlo,
    const unsigned short* __restrict__ Khi, const unsigned short* __restrict__ Klo,
    float* __restrict__ S, float2* __restrict__ stats, const int* __restrict__ causal_p) {
  // flat dispatch id (x fastest); nwg = 2048, divisible by 8.
  int f = (blockIdx.z * 16 + blockIdx.y) * 16 + blockIdx.x;
  int lf = (f & 7) * 256 + (f >> 3);   // XCD j owns logical [j*256,(j+1)*256)
  int b = lf >> 8;
  int k0 = ((lf >> 4) & 15) * 128;
  int l0 = (lf & 15) * 128;
  int causal = *causal_p;
  int t = threadIdx.x;
  float* Sb = S + (size_t)b * W_ * W_;

  if (causal && (l0 + 127 < k0)) {   // tile fully below diagonal: fill, no stats
    float4 nb = make_float4(NEG_BIG_, NEG_BIG_, NEG_BIG_, NEG_BIG_);
    int row = t >> 1, c0 = (t & 1) * 64;
#pragma unroll
    for (int j = 0; j < 16; j++)
      *(float4*)&Sb[(size_t)(k0 + row) * W_ + l0 + c0 + j * 4] = nb;
    return;
  }

  __shared__ __align__(16) unsigned short qh_s[128 * 32], ql_s[128 * 32];
  __shared__ __align__(16) unsigned short kh_s[128 * 32], kl_s[128 * 32];
  __shared__ float sm_h[2][128], ss_h[2][128];

  int wave = t >> 6, lane = t & 63;
  int wk0 = (wave >> 1) * 64, wl0 = (wave & 1) * 64;
  int lr = lane & 15, lq = lane >> 4;

  const unsigned short* Qhb = Qhi + ((size_t)b * W_ + k0) * D_;
  const unsigned short* Qlb = Qlo + ((size_t)b * W_ + k0) * D_;
  const unsigned short* Khb = Khi + ((size_t)b * W_ + l0) * D_;
  const unsigned short* Klb = Klo + ((size_t)b * W_ + l0) * D_;

  // staging: 512 slots = 128 rows x 4 chunks; thread owns slots t, t+256.
  int srow0 = t >> 2, sq = t & 3;
  int srow1 = srow0 + 64;
  size_t g0 = (size_t)srow0 * D_ + ((sq ^ ((srow0 >> 1) & 3)) << 3);
  size_t g1 = (size_t)srow1 * D_ + ((sq ^ ((srow1 >> 1) & 3)) << 3);
  int a0 = t * 8, a1 = t * 8 + 2048;   // shorts

  f32x4 acc[4][4];
#pragma unroll
  for (int i = 0; i < 4; i++)
#pragma unroll
    for (int j = 0; j < 4; j++) acc[i][j] = (f32x4){0.f, 0.f, 0.f, 0.f};

  for (int d0 = 0; d0 < D_; d0 += 32) {
    gl16(Qhb + g0 + d0, &qh_s[a0]);
    gl16(Qhb + g1 + d0, &qh_s[a1]);
    gl16(Qlb + g0 + d0, &ql_s[a0]);
    gl16(Qlb + g1 + d0, &ql_s[a1]);
    gl16(Khb + g0 + d0, &kh_s[a0]);
    gl16(Khb + g1 + d0, &kh_s[a1]);
    gl16(Klb + g0 + d0, &kl_s[a0]);
    gl16(Klb + g1 + d0, &kl_s[a1]);
    __syncthreads();   // drains vmcnt for global_load_lds

    bf16x8 ah[4], al[4], bh[4], bl[4];
#pragma unroll
    for (int mt = 0; mt < 4; mt++) {
      int a = swz(wk0 + mt * 16 + lr, lq);
      ah[mt] = *(const bf16x8*)&qh_s[a];
      al[mt] = *(const bf16x8*)&ql_s[a];
    }
#pragma unroll
    for (int nt = 0; nt < 4; nt++) {
      int a = swz(wl0 + nt * 16 + lr, lq);
      bh[nt] = *(const bf16x8*)&kh_s[a];
      bl[nt] = *(const bf16x8*)&kl_s[a];
    }
    __builtin_amdgcn_s_setprio(1);
#pragma unroll
    for (int mt = 0; mt < 4; mt++)
#pragma unroll
      for (int nt = 0; nt < 4; nt++) {
        acc[mt][nt] = __builtin_amdgcn_mfma_f32_16x16x32_bf16(ah[mt], bh[nt], acc[mt][nt], 0, 0, 0);
        acc[mt][nt] = __builtin_amdgcn_mfma_f32_16x16x32_bf16(ah[mt], bl[nt], acc[mt][nt], 0, 0, 0);
        acc[mt][nt] = __builtin_amdgcn_mfma_f32_16x16x32_bf16(al[mt], bh[nt], acc[mt][nt], 0, 0, 0);
      }
    __builtin_amdgcn_s_setprio(0);
    __syncthreads();
  }

  // epilogue: store masked scores + per-row half-tile stats (64-col reduce).
  int wh = wl0 >> 6;
#pragma unroll
  for (int mt = 0; mt < 4; mt++)
#pragma unroll
    for (int r = 0; r < 4; r++) {
      int rr = wk0 + mt * 16 + lq * 4 + r;
      int k = k0 + rr;
      float v4[4];
#pragma unroll
      for (int nt = 0; nt < 4; nt++) {
        int l = l0 + wl0 + nt * 16 + lr;
        float s = acc[mt][nt][r] * SCALE_;
        if (causal && (l < k || s == 0.0f)) s = NEG_BIG_;  // faithful triu + zero->mask
        Sb[(size_t)k * W_ + l] = s;
        v4[nt] = s;
      }
      float mx = fmaxf(fmaxf(v4[0], v4[1]), fmaxf(v4[2], v4[3]));
#pragma unroll
      for (int off = 1; off < 16; off <<= 1) mx = fmaxf(mx, __shfl_xor(mx, off, 64));
      float ss = __expf(v4[0] - mx) + __expf(v4[1] - mx) +
                 __expf(v4[2] - mx) + __expf(v4[3] - mx);
#pragma unroll
      for (int off = 1; off < 16; off <<= 1) ss += __shfl_xor(ss, off, 64);
      if (lr == 0) { sm_h[wh][rr] = mx; ss_h[wh][rr] = ss; }
    }
  __syncthreads();
  if (t < 128) {
    float m0 = sm_h[0][t], m1 = sm_h[1][t];
    float s0 = ss_h[0][t], s1 = ss_h[1][t];
    float m = fmaxf(m0, m1);
    float ssum = s0 * __expf(m0 - m) + s1 * __expf(m1 - m);
    stats[((size_t)b * W_ + k0 + t) * 16 + (l0 >> 7)] = make_float2(m, ssum);
  }
}

// ---- combine per-tile stats -> mrow, invrow (replaces big softmax pass) ----
__global__ __launch_bounds__(256) void combine_stats(
    const float2* __restrict__ stats, float* __restrict__ mrow,
    float* __restrict__ invrow, const int* __restrict__ causal_p) {
  int row = blockIdx.x * 256 + threadIdx.x;   // B_*W_ = 16384
  int k = row & (W_ - 1);
  int lt0 = (*causal_p) ? (k >> 7) : 0;
  const float2* sp = stats + (size_t)row * 16;
  float m = -INFINITY;
  for (int lt = lt0; lt < 16; lt++) m = fmaxf(m, sp[lt].x);
  float s = 0.f;
  for (int lt = lt0; lt < 16; lt++) s += sp[lt].y * __expf(sp[lt].x - m);
  mrow[row] = m;
  invrow[row] = 1.0f / s;
}

// ---- out: O[d][k] = sum_l V[d][l] * P[k][l], P = exp(S-m)*inv (split bf16) ----
// Block = (b, k0 of 128, d-quarter of 128). 256 threads = 4 waves of 64d x 64k.
// Grid 512 = 2 blocks/CU; within-XCD dispatch order k0-ascending = LPT
// (biggest jobs first) -> balanced makespan (~68 chunks/CU vs 64-chunk tail).
// Pipeline: S prefetch dist 2 (named E/O reg sets), writeP BEFORE MFMAs,
// V DMA dbuf, one barrier per chunk, setprio.
__global__ __launch_bounds__(256) void out_bal(
    const unsigned short* __restrict__ Vhi, const unsigned short* __restrict__ Vlo,
    const float* __restrict__ S,
    const float* __restrict__ mrow, const float* __restrict__ invrow,
    float* __restrict__ O, const int* __restrict__ causal_p) {
  // flat id: grid (64,1,8) -> f = z*64 + x; nwg = 512, divisible by 8.
  int f = blockIdx.z * 64 + blockIdx.x;
  int lf = (f & 7) * 64 + (f >> 3);    // XCD j owns logical [j*64,(j+1)*64)
  int b = lf >> 6;
  int j2 = lf & 63;
  int k0 = (j2 >> 2) * 128;            // ascending within XCD -> LPT
  int dq = j2 & 3;                     // d-quarter: rows [dq*128, dq*128+128)
  int causal = *causal_p;
  int t = threadIdx.x;
  int wave = t >> 6, lane = t & 63;
  int wd0 = (wave >> 1) * 64;          // 0,64 within the 128-d quarter
  int wk0 = (wave & 1) * 64;           // 0,64 within the 128-k tile
  int lr = lane & 15, lq = lane >> 4;

  __shared__ __align__(16) unsigned short vh_s[2][128 * 32], vl_s[2][128 * 32];  // 32 KB
  __shared__ __align__(16) unsigned short ph_s[2][128 * 32], pl_s[2][128 * 32];  // 32 KB

  const unsigned short* Vhb = Vhi + ((size_t)b * D_ + dq * 128) * W_;
  const unsigned short* Vlb = Vlo + ((size_t)b * D_ + dq * 128) * W_;
  const float* Sb = S + (size_t)b * W_ * W_;

  // V staging: 512 slots = 128 rows x 4 chunks; thread owns slots t, t+256.
  // f(row) invariant under row+64 -> same XOR for both rows.
  int rA = t >> 2, qc = t & 3;
  int vx = (qc ^ ((rA >> 1) & 3)) << 3;
  const unsigned short* VhA = Vhb + (size_t)rA * W_ + vx;
  const unsigned short* VhB = VhA + (size_t)64 * W_;
  const unsigned short* VlA = Vlb + (size_t)rA * W_ + vx;
  const unsigned short* VlB = VlA + (size_t)64 * W_;
  int a0 = t * 8, a1 = t * 8 + 2048;   // linear LDS dest (shorts)

  // P staging: rows rA and rA+64, chunk qc; swizzled ds_write addrs.
  const float* SrowA = Sb + (size_t)(k0 + rA) * W_ + qc * 8;
  const float* SrowB = SrowA + (size_t)64 * W_;
  int pA = rA * 32 + vx;               // same xor (qc, f(rA)) as V
  int pB = pA + 64 * 32;
  float mA = mrow[(size_t)b * W_ + k0 + rA], iA = invrow[(size_t)b * W_ + k0 + rA];
  float mB = mrow[(size_t)b * W_ + k0 + rA + 64], iB = invrow[(size_t)b * W_ + k0 + rA + 64];

  f32x4 acc[4][4];
#pragma unroll
  for (int i = 0; i < 4; i++)
#pragma unroll
    for (int j = 0; j < 4; j++) acc[i][j] = (f32x4){0.f, 0.f, 0.f, 0.f};

  int lstart = causal ? k0 : 0;        // P[k][l]=0 for l<k (S holds NEG_BIG there)
  int nch = (W_ - lstart) >> 5;        // multiple of 4

  auto stageV = [&](int buf, int l) {
    gl16(VhA + l, &vh_s[buf][a0]);
    gl16(VhB + l, &vh_s[buf][a1]);
    gl16(VlA + l, &vl_s[buf][a0]);
    gl16(VlB + l, &vl_s[buf][a1]);
  };
  auto writeP = [&](unsigned short* __restrict__ ph, unsigned short* __restrict__ pl,
                    float4 sa0, float4 sa1, float4 sb0, float4 sb1) {
    float p[8];
    unsigned short hi8[8] __attribute__((aligned(16)));
    unsigned short lo8[8] __attribute__((aligned(16)));
    p[0] = __expf(sa0.x - mA) * iA; p[1] = __expf(sa0.y - mA) * iA;
    p[2] = __expf(sa0.z - mA) * iA; p[3] = __expf(sa0.w - mA) * iA;
    p[4] = __expf(sa1.x - mA) * iA; p[5] = __expf(sa1.y - mA) * iA;
    p[6] = __expf(sa1.z - mA) * iA; p[7] = __expf(sa1.w - mA) * iA;
#pragma unroll
    for (int j = 0; j < 8; j++) split2(p[j], hi8[j], lo8[j]);
    *(uint4*)&ph[pA] = *(uint4*)hi8;
    *(uint4*)&pl[pA] = *(uint4*)lo8;
    p[0] = __expf(sb0.x - mB) * iB; p[1] = __expf(sb0.y - mB) * iB;
    p[2] = __expf(sb0.z - mB) * iB; p[3] = __expf(sb0.w - mB) * iB;
    p[4] = __expf(sb1.x - mB) * iB; p[5] = __expf(sb1.y - mB) * iB;
    p[6] = __expf(sb1.z - mB) * iB; p[7] = __expf(sb1.w - mB) * iB;
#pragma unroll
    for (int j = 0; j < 8; j++) split2(p[j], hi8[j], lo8[j]);
    *(uint4*)&ph[pB] = *(uint4*)hi8;
    *(uint4*)&pl[pB] = *(uint4*)lo8;
  };
  auto compute = [&](const unsigned short* vh, const unsigned short* vl,
                     const unsigned short* ph, const unsigned short* pl) {
    bf16x8 ah[4], al[4], bh[4], bl[4];
#pragma unroll
    for (int mt = 0; mt < 4; mt++) {
      int a = swz(wd0 + mt * 16 + lr, lq);
      ah[mt] = *(const bf16x8*)&vh[a];
      al[mt] = *(const bf16x8*)&vl[a];
    }
#pragma unroll
    for (int nt = 0; nt < 4; nt++) {
      int a = swz(wk0 + nt * 16 + lr, lq);
      bh[nt] = *(const bf16x8*)&ph[a];
      bl[nt] = *(const bf16x8*)&pl[a];
    }
    __builtin_amdgcn_s_setprio(1);
#pragma unroll
    for (int mt = 0; mt < 4; mt++)
#pragma unroll
      for (int nt = 0; nt < 4; nt++) {
        acc[mt][nt] = __builtin_amdgcn_mfma_f32_16x16x32_bf16(ah[mt], bh[nt], acc[mt][nt], 0, 0, 0);
        acc[mt][nt] = __builtin_amdgcn_mfma_f32_16x16x32_bf16(ah[mt], bl[nt], acc[mt][nt], 0, 0, 0);
        acc[mt][nt] = __builtin_amdgcn_mfma_f32_16x16x32_bf16(al[mt], bh[nt], acc[mt][nt], 0, 0, 0);
      }
    __builtin_amdgcn_s_setprio(0);
  };

  // S registers: even/odd chunk sets (named, no runtime indexing).
  float4 sAE0, sAE1, sBE0, sBE1, sAO0, sAO1, sBO0, sBO1;

  // prologue: S(0),S(1) in regs; V(0) DMA; P(0) written (waits S(0) once).
  sAE0 = *(const float4*)&SrowA[lstart];      sAE1 = *(const float4*)&SrowA[lstart + 4];
  sBE0 = *(const float4*)&SrowB[lstart];      sBE1 = *(const float4*)&SrowB[lstart + 4];
  sAO0 = *(const float4*)&SrowA[lstart + 32]; sAO1 = *(const float4*)&SrowA[lstart + 36];
  sBO0 = *(const float4*)&SrowB[lstart + 32]; sBO1 = *(const float4*)&SrowB[lstart + 36];
  stageV(0, lstart);
  writeP(&ph_s[0][0], &pl_s[0][0], sAE0, sAE1, sBE0, sBE1);
  __syncthreads();

  for (int ci = 0; ci < nch; ci += 2) {
    int base = lstart + ci * 32;
    // ---- even chunk ci: consumes buf0 ----
    if (ci + 2 < nch) {                // S(ci+2) -> E set
      sAE0 = *(const float4*)&SrowA[base + 64]; sAE1 = *(const float4*)&SrowA[base + 68];
      sBE0 = *(const float4*)&SrowB[base + 64]; sBE1 = *(const float4*)&SrowB[base + 68];
    }
    stageV(1, base + 32);              // V(ci+1) DMA (lands during this chunk)
    writeP(&ph_s[1][0], &pl_s[1][0], sAO0, sAO1, sBO0, sBO1);  // P(ci+1)
    compute(&vh_s[0][0], &vl_s[0][0], &ph_s[0][0], &pl_s[0][0]);
    __syncthreads();
    // ---- odd chunk ci+1: consumes buf1 ----
    bool more = (ci + 2 < nch);
    if (ci + 3 < nch) {                // S(ci+3) -> O set
      sAO0 = *(const float4*)&SrowA[base + 96]; sAO1 = *(const float4*)&SrowA[base + 100];
      sBO0 = *(const float4*)&SrowB[base + 96]; sBO1 = *(const float4*)&SrowB[base + 100];
    }
    if (more) {
      stageV(0, base + 64);            // V(ci+2) DMA
      writeP(&ph_s[0][0], &pl_s[0][0], sAE0, sAE1, sBE0, sBE1); // P(ci+2)
    }
    compute(&vh_s[1][0], &vl_s[1][0], &ph_s[1][0], &pl_s[1][0]);
    __syncthreads();
  }

#pragma unroll
  for (int mt = 0; mt < 4; mt++)
#pragma unroll
    for (int nt = 0; nt < 4; nt++)
#pragma unroll
      for (int r = 0; r < 4; r++) {
        int d = dq * 128 + wd0 + mt * 16 + lq * 4 + r;
        int k = k0 + wk0 + nt * 16 + lr;
        O[((size_t)b * D_ + d) * W_ + k] = acc[mt][nt][r];
      }
}

extern "C" void kernel_launch(void* const* d_in, const int* in_sizes, int n_in,
                              void* d_out, int out_size, void* d_ws, size_t ws_size,
                              hipStream_t stream) {
  const float* x  = (const float*)d_in[0];
  const float* Wq = (const float*)d_in[1];
  const float* bq = (const float*)d_in[2];
  const float* Wk = (const float*)d_in[3];
  const float* bk = (const float*)d_in[4];
  const float* Wv = (const float*)d_in[5];
  const float* bv = (const float*)d_in[6];
  const int* causal = (const int*)d_in[7];

  float* out = (float*)d_out;
  float* x_out = out;                                   // 8*512*2048
  float* S = out + (size_t)B_ * D_ * W_;                // 8*2048*2048

  const size_t NQ = (size_t)B_ * W_ * D_;               // 8,388,608
  unsigned short* wsu = (unsigned short*)d_ws;
  unsigned short* Qhi = wsu;
  unsigned short* Qlo = wsu + NQ;
  unsigned short* Khi = wsu + 2 * NQ;
  unsigned short* Klo = wsu + 3 * NQ;
  unsigned short* Vhi = wsu + 4 * NQ;
  unsigned short* Vlo = wsu + 5 * NQ;
  float* mrow   = (float*)(wsu + 6 * NQ);               // B_*W_ = 16384
  float* invrow = mrow + (size_t)B_ * W_;
  float2* stats = (float2*)(invrow + (size_t)B_ * W_);  // B_*W_*16 float2 = 2 MB

  proj_qk<<<4096, 256, 0, stream>>>(x, Wq, bq, Wk, bk, Qhi, Qlo, Khi, Klo);
  proj_v<<<4096, 256, 0, stream>>>(x, Wv, bv, Vhi, Vlo);
  scores_mfma<<<dim3(16, 16, B_), 256, 0, stream>>>(Qhi, Qlo, Khi, Klo, S, stats, causal);
  combine_stats<<<64, 256, 0, stream>>>(stats, mrow, invrow, causal);
  out_bal<<<dim3(64, 1, B_), 256, 0, stream>>>(Vhi, Vlo, S, mrow, invrow, x_out, causal);
}